// Round 3
// baseline (100.013 us; speedup 1.0000x reference)
//
#include <hip/hip_runtime.h>
#include <math.h>

// ---------------- problem constants ----------------
constexpr int B  = 2, C = 64, H = 128, W = 128;
constexpr int Cr = 16;
constexpr int K  = 7, KK = 49;
constexpr int HW  = H * W;
constexpr int CHW = C * HW;
constexpr int NPIX = B * HW;       // 32768
constexpr float EPS = 1e-5f;

// ---- fast-path ws layout (floats): r[NPIX][16] | partial[512*32] | stats[32] | counter
constexpr int R_F = NPIX * Cr;     // 524288
constexpr int P_F = 512 * 32;      // 16384
constexpr size_t WS_NEED = (size_t)(R_F + P_F + 64) * 4;

// ==================== FAST PATH ====================

// A: r = X . w_reduce + b_reduce, per-block stats partials, last-block stats finalize.
// grid 512 x 256: block = 64 pixels x 4 channel-groups(16ch).
__global__ __launch_bounds__(256) void k_reduce_r2(
    const float* __restrict__ X, const float* __restrict__ w_reduce,
    const float* __restrict__ b_reduce, const float* __restrict__ gamma,
    const float* __restrict__ beta, float* __restrict__ r_ws,
    float* __restrict__ partial, float* __restrict__ stats,
    unsigned int* __restrict__ counter)
{
    __shared__ float wrS[Cr * C];
    __shared__ float tmpA[4][Cr][64];
    __shared__ unsigned int lastS;
    __shared__ float red[8][32];
    __shared__ float fin[32];

    const int t = threadIdx.x;
    for (int i = t; i < Cr * C; i += 256) wrS[i] = w_reduce[i];
    __syncthreads();

    const int pixl = t & 63, cg = t >> 6;
    const int p = blockIdx.x * 64 + pixl;
    const int b = p >> 14, hw = p & (HW - 1);
    const float* xb = X + (size_t)b * CHW + hw;

    float x[16];
    #pragma unroll
    for (int i = 0; i < 16; ++i) x[i] = xb[(cg * 16 + i) * HW];

    float rp[16];
    #pragma unroll
    for (int o = 0; o < 16; ++o) rp[o] = (cg == 0) ? b_reduce[o] : 0.f;
    #pragma unroll
    for (int i = 0; i < 16; ++i) {
        const float xv = x[i];
        #pragma unroll
        for (int o = 0; o < 16; ++o)
            rp[o] = fmaf(xv, wrS[o * 64 + cg * 16 + i], rp[o]);
    }
    #pragma unroll
    for (int o = 0; o < 16; ++o) tmpA[cg][o][pixl] = rp[o];
    __syncthreads();

    float rr[4];
    #pragma unroll
    for (int j = 0; j < 4; ++j) {
        const int o = cg * 4 + j;
        rr[j] = tmpA[0][o][pixl] + tmpA[1][o][pixl] + tmpA[2][o][pixl] + tmpA[3][o][pixl];
    }
    *(float4*)&r_ws[(size_t)p * 16 + cg * 4] = make_float4(rr[0], rr[1], rr[2], rr[3]);

    float s[4], q[4];
    #pragma unroll
    for (int j = 0; j < 4; ++j) { s[j] = rr[j]; q[j] = rr[j] * rr[j]; }
    #pragma unroll
    for (int off = 32; off > 0; off >>= 1) {
        #pragma unroll
        for (int j = 0; j < 4; ++j) {
            s[j] += __shfl_down(s[j], off);
            q[j] += __shfl_down(q[j], off);
        }
    }
    if ((t & 63) == 0) {
        #pragma unroll
        for (int j = 0; j < 4; ++j) {
            partial[blockIdx.x * 32 + cg * 4 + j]      = s[j];
            partial[blockIdx.x * 32 + 16 + cg * 4 + j] = q[j];
        }
    }
    // release: make partial visible device-wide, then count this block done
    __threadfence();
    __syncthreads();
    if (t == 0) lastS = atomicAdd(counter, 1u);
    __syncthreads();

    if (lastS == 511u) {           // last block finalizes stats (fixed order -> deterministic)
        __threadfence();           // acquire
        const int o = t & 31, seg = t >> 5;
        float acc = 0.f;
        #pragma unroll 16
        for (int j = 0; j < 64; ++j) acc += partial[(seg * 64 + j) * 32 + o];
        red[seg][o] = acc;
        __syncthreads();
        if (t < 32) {
            float v = 0.f;
            #pragma unroll
            for (int g = 0; g < 8; ++g) v += red[g][t];
            fin[t] = v;
        }
        __syncthreads();
        if (t < 16) {
            const float mean = fin[t] / (float)NPIX;
            const float var  = fin[16 + t] / (float)NPIX - mean * mean;
            const float sc   = gamma[t] * rsqrtf(var + EPS);
            stats[t]      = sc;
            stats[16 + t] = beta[t] - mean * sc;
        }
    }
}

// C: fused act/kc + involution. block = (b, half(32ch), 16w x 8h tile), 256 thr, grid 512.
constexpr int TLH = 8, TLW = 16;        // tile
constexpr int HR = TLH + 6, HC = TLW + 6;   // halo 14 x 22
constexpr int RPT = 24;                 // row pitch (floats)
constexpr int CSP = HR * RPT + 4;       // 340: 4*CSP%32=16 -> chg groups split banks
constexpr int XS2_F  = 32 * CSP;        // 10880
constexpr int KC2_F  = KK * 128;        // 6272
constexpr int ACT2_F = Cr * 128;        // 2048
constexpr int WSP_F  = KK * Cr;         // 784
constexpr int SMEM2_F = XS2_F + KC2_F + ACT2_F + WSP_F + 52;   // 20036
constexpr int SMEM2_BYTES = SMEM2_F * 4;                       // 80144 -> 2 blocks/CU

__global__ __launch_bounds__(256) void k_inv2(
    const float* __restrict__ X, const float* __restrict__ r_ws,
    const float* __restrict__ stats, const float* __restrict__ w_span,
    const float* __restrict__ b_span, float* __restrict__ out)
{
    extern __shared__ float smem[];
    float* Xs   = smem;                  // [c][r*24+col] (+4 pad per ch)
    float* kcS  = Xs + XS2_F;            // [k][128]
    float* actS = kcS + KC2_F;           // [o][128]
    float* wspS = actS + ACT2_F;         // [k][o]
    float* bspS = wspS + WSP_F;          // [49]

    const int t   = threadIdx.x;
    const int raw = blockIdx.x;
    const int wg  = (raw & 7) * 64 + (raw >> 3);    // bijective XCD swizzle (512%8==0)
    const int tile = wg & 127;
    const int half = (wg >> 7) & 1;
    const int b    = wg >> 8;
    const int th0 = (tile >> 3) * TLH;
    const int tw0 = (tile & 7) * TLW;

    // ---- ph1 global loads issued early (latency hides under staging) ----
    const int px1 = t & 127;             // tile pixel (row-major 8x16)
    const int oq2 = (t >> 7) * 2;        // which pair of o-quads
    const int p1r = px1 >> 4, p1c = px1 & 15;
    const size_t gp = (size_t)b * HW + (size_t)(th0 + p1r) * W + (tw0 + p1c);
    const float4 ra = *(const float4*)&r_ws[gp * 16 + oq2 * 4];
    const float4 rb = *(const float4*)&r_ws[gp * 16 + oq2 * 4 + 4];
    const float4 sa = *(const float4*)&stats[oq2 * 4];
    const float4 sb = *(const float4*)&stats[oq2 * 4 + 4];
    const float4 oa = *(const float4*)&stats[16 + oq2 * 4];
    const float4 ob4 = *(const float4*)&stats[16 + oq2 * 4 + 4];

    // ---- ph0: stage X halo (32 ch), div-free addressing ----
    {
        const int scol = t & 31;         // 0..31, cols 0..21 valid
        const int sch  = t >> 5;         // 0..7
        const int gw   = tw0 + scol - 3;
        const bool wok = (unsigned)gw < (unsigned)W && scol < HC;
        const float* xg = X + (size_t)b * CHW + (size_t)(half * 32) * HW;
        #pragma unroll
        for (int cb = 0; cb < 4; ++cb) {
            const int c = cb * 8 + sch;
            const float* xc = xg + (size_t)c * HW;
            float* xs = Xs + c * CSP + scol;
            #pragma unroll
            for (int r = 0; r < HR; ++r) {
                const int gh = th0 + r - 3;
                float v = 0.f;
                if (wok && (unsigned)gh < (unsigned)H) v = xc[gh * W + gw];
                if (scol < HC) xs[r * RPT] = v;
            }
        }
    }
    for (int i = t; i < WSP_F; i += 256) wspS[i] = w_span[i];
    if (t < KK) bspS[t] = b_span[t];

    // ---- ph1: act = relu(sc*r + of) (no Xs dependency -> before first sync) ----
    actS[(oq2 * 4 + 0) * 128 + px1] = fmaxf(fmaf(sa.x, ra.x, oa.x), 0.f);
    actS[(oq2 * 4 + 1) * 128 + px1] = fmaxf(fmaf(sa.y, ra.y, oa.y), 0.f);
    actS[(oq2 * 4 + 2) * 128 + px1] = fmaxf(fmaf(sa.z, ra.z, oa.z), 0.f);
    actS[(oq2 * 4 + 3) * 128 + px1] = fmaxf(fmaf(sa.w, ra.w, oa.w), 0.f);
    actS[(oq2 * 4 + 4) * 128 + px1] = fmaxf(fmaf(sb.x, rb.x, ob4.x), 0.f);
    actS[(oq2 * 4 + 5) * 128 + px1] = fmaxf(fmaf(sb.y, rb.y, ob4.y), 0.f);
    actS[(oq2 * 4 + 6) * 128 + px1] = fmaxf(fmaf(sb.z, rb.z, ob4.z), 0.f);
    actS[(oq2 * 4 + 7) * 128 + px1] = fmaxf(fmaf(sb.w, rb.w, ob4.w), 0.f);
    __syncthreads();

    // ---- ph2: 49 kernel coefficients per pixel ----
    {
        float act[16];
        #pragma unroll
        for (int o = 0; o < 16; ++o) act[o] = actS[o * 128 + px1];
        const int kg = t >> 7;           // uniform per wave
        for (int k = kg; k < KK; k += 2) {
            float v = bspS[k];
            #pragma unroll
            for (int o = 0; o < 16; ++o) v = fmaf(act[o], wspS[k * 16 + o], v);
            kcS[k * 128 + px1] = v;
        }
    }
    __syncthreads();

    // ---- ph3: involution. thread = 4px x 4ch ----
    const int strip = t & 31;            // 8 rows x 4 col-groups
    const int chg   = t >> 5;            // 0..7 -> 4 channels each
    const int pr3 = strip >> 2, pc = (strip & 3) * 4;
    const int c0  = chg * 4;

    float acc[4][4];
    #pragma unroll
    for (int i = 0; i < 4; ++i)
        #pragma unroll
        for (int j = 0; j < 4; ++j) acc[i][j] = 0.f;

    #pragma unroll
    for (int kh = 0; kh < 7; ++kh) {
        float4 kcr[7];
        #pragma unroll
        for (int kw = 0; kw < 7; ++kw)
            kcr[kw] = *(const float4*)&kcS[(kh * 7 + kw) * 128 + pr3 * 16 + pc];
        const float* kf = (const float*)kcr;
        #pragma unroll
        for (int i = 0; i < 4; ++i) {
            const float* xr = &Xs[(c0 + i) * CSP + (pr3 + kh) * RPT + pc];
            const float4 xa = *(const float4*)&xr[0];
            const float4 xb = *(const float4*)&xr[4];
            const float4 xc = *(const float4*)&xr[8];
            const float xw[12] = {xa.x, xa.y, xa.z, xa.w,
                                  xb.x, xb.y, xb.z, xb.w,
                                  xc.x, xc.y, xc.z, xc.w};
            #pragma unroll
            for (int kw = 0; kw < 7; ++kw)
                #pragma unroll
                for (int j = 0; j < 4; ++j)
                    acc[i][j] = fmaf(kf[kw * 4 + j], xw[kw + j], acc[i][j]);
        }
    }

    float* ob = out + (size_t)b * CHW + (size_t)(half * 32 + c0) * HW
                    + (size_t)(th0 + pr3) * W + (tw0 + pc);
    #pragma unroll
    for (int i = 0; i < 4; ++i)
        *(float4*)&ob[(size_t)i * HW] = make_float4(acc[i][0], acc[i][1], acc[i][2], acc[i][3]);
}

// ==================== FALLBACK PATH (round-1, passing) ====================

constexpr int XS_F  = C * 196;
constexpr int KC_F  = KK * 64;
constexpr int ACT_F = Cr * 64;
constexpr int WR_F  = Cr * C;
constexpr int SMEM_F = XS_F + KC_F + ACT_F + WR_F + WSP_F + KK + Cr + Cr;
constexpr int SMEM_BYTES = SMEM_F * 4;

__global__ __launch_bounds__(128) void k_reduce_stats(
    const float* __restrict__ X, const float* __restrict__ w_reduce,
    const float* __restrict__ b_reduce, float* __restrict__ partial)
{
    __shared__ float wr[WR_F];
    __shared__ float brd[Cr];
    __shared__ float tmp[2][32];
    const int t = threadIdx.x;
    for (int i = t; i < WR_F; i += 128) wr[i] = w_reduce[i];
    if (t < Cr) brd[t] = b_reduce[t];
    __syncthreads();
    const int p  = blockIdx.x * 128 + t;
    const int b  = p >> 14;
    const int hw = p & (HW - 1);
    const float* xb = X + b * CHW + hw;
    float r[Cr];
    #pragma unroll
    for (int o = 0; o < Cr; ++o) r[o] = brd[o];
    #pragma unroll 4
    for (int c = 0; c < C; ++c) {
        const float x = xb[c * HW];
        #pragma unroll
        for (int o = 0; o < Cr; ++o) r[o] = fmaf(x, wr[o * C + c], r[o]);
    }
    const int lane = t & 63, wv = t >> 6;
    #pragma unroll
    for (int o = 0; o < Cr; ++o) {
        float s = r[o], q = r[o] * r[o];
        #pragma unroll
        for (int off = 32; off > 0; off >>= 1) {
            s += __shfl_down(s, off);
            q += __shfl_down(q, off);
        }
        if (lane == 0) { tmp[wv][o] = s; tmp[wv][Cr + o] = q; }
    }
    __syncthreads();
    if (t < 32) partial[blockIdx.x * 32 + t] = tmp[0][t] + tmp[1][t];
}

__global__ __launch_bounds__(256) void k_stats_final(
    const float* __restrict__ partial, float* __restrict__ stats)
{
    __shared__ float red[256];
    __shared__ float fin[32];
    const int t = threadIdx.x;
    const int o = t & 31, g = t >> 5;
    float acc = 0.f;
    #pragma unroll 8
    for (int j = 0; j < 32; ++j) acc += partial[(g * 32 + j) * 32 + o];
    red[t] = acc;
    __syncthreads();
    if (t < 32) {
        float v = 0.f;
        #pragma unroll
        for (int g2 = 0; g2 < 8; ++g2) v += red[g2 * 32 + t];
        fin[t] = v;
    }
    __syncthreads();
    if (t < Cr) {
        const float mean = fin[t] / (float)NPIX;
        const float var  = fin[Cr + t] / (float)NPIX - mean * mean;
        stats[t]      = mean;
        stats[Cr + t] = rsqrtf(var + EPS);
    }
}

__global__ __launch_bounds__(256) void k_involution(
    const float* __restrict__ X, const float* __restrict__ w_reduce,
    const float* __restrict__ b_reduce, const float* __restrict__ gamma,
    const float* __restrict__ beta, const float* __restrict__ w_span,
    const float* __restrict__ b_span, const float* __restrict__ stats,
    float* __restrict__ out)
{
    extern __shared__ float smem[];
    float* Xs   = smem;
    float* kcS  = Xs  + XS_F;
    float* actS = kcS + KC_F;
    float* wrS  = actS + ACT_F;
    float* wspS = wrS + WR_F;
    float* bspS = wspS + WSP_F;
    float* scS  = bspS + KK;
    float* ofS  = scS + Cr;
    const int t    = threadIdx.x;
    const int bx   = blockIdx.x;
    const int b    = bx >> 8;
    const int tile = bx & 255;
    const int h0   = (tile >> 4) << 3;
    const int w0   = (tile & 15) << 3;
    const float* xbg = X + b * CHW;
    for (int idx = t; idx < XS_F; idx += 256) {
        const int c   = idx / 196;
        const int rem = idx - c * 196;
        const int r   = rem / 14;
        const int col = rem - r * 14;
        const int gh  = h0 + r - 3, gw = w0 + col - 3;
        float v = 0.f;
        if ((unsigned)gh < (unsigned)H && (unsigned)gw < (unsigned)W)
            v = xbg[c * HW + gh * W + gw];
        Xs[idx] = v;
    }
    for (int i = t; i < WR_F;  i += 256) wrS[i]  = w_reduce[i];
    for (int i = t; i < WSP_F; i += 256) wspS[i] = w_span[i];
    if (t < KK) bspS[t] = b_span[t];
    if (t < Cr) {
        const float m  = stats[t];
        const float rs = stats[Cr + t];
        const float gm = gamma[t];
        scS[t] = gm * rs;
        ofS[t] = (b_reduce[t] - m) * gm * rs + beta[t];
    }
    __syncthreads();
    const int pix = t & 63;
    const int grp = t >> 6;
    const int ph  = pix >> 3, pw = pix & 7;
    {
        const int base = (ph + 3) * 14 + (pw + 3);
        float d0 = 0.f, d1 = 0.f, d2 = 0.f, d3 = 0.f;
        #pragma unroll 8
        for (int c = 0; c < C; ++c) {
            const float x = Xs[c * 196 + base];
            d0 = fmaf(x, wrS[(grp * 4 + 0) * C + c], d0);
            d1 = fmaf(x, wrS[(grp * 4 + 1) * C + c], d1);
            d2 = fmaf(x, wrS[(grp * 4 + 2) * C + c], d2);
            d3 = fmaf(x, wrS[(grp * 4 + 3) * C + c], d3);
        }
        const float d[4] = {d0, d1, d2, d3};
        #pragma unroll
        for (int j = 0; j < 4; ++j) {
            const int o = grp * 4 + j;
            actS[o * 64 + pix] = fmaxf(fmaf(scS[o], d[j], ofS[o]), 0.f);
        }
    }
    __syncthreads();
    for (int k = grp; k < KK; k += 4) {
        float v = bspS[k];
        #pragma unroll
        for (int o = 0; o < Cr; ++o)
            v = fmaf(actS[o * 64 + pix], wspS[k * Cr + o], v);
        kcS[k * 64 + pix] = v;
    }
    __syncthreads();
    float acc[16];
    #pragma unroll
    for (int i = 0; i < 16; ++i) acc[i] = 0.f;
    const float* xsc = Xs + grp * 16 * 196;
    #pragma unroll
    for (int k = 0; k < KK; ++k) {
        const int kh = k / 7, kw = k - (k / 7) * 7;
        const float kcv = kcS[k * 64 + pix];
        const int xoff = (ph + kh) * 14 + (pw + kw);
        #pragma unroll
        for (int i = 0; i < 16; ++i)
            acc[i] = fmaf(kcv, xsc[i * 196 + xoff], acc[i]);
    }
    float* ob = out + b * CHW + (grp * 16) * HW + (h0 + ph) * W + (w0 + pw);
    #pragma unroll
    for (int i = 0; i < 16; ++i) ob[i * HW] = acc[i];
}

// ==================== launch ====================

extern "C" void kernel_launch(void* const* d_in, const int* in_sizes, int n_in,
                              void* d_out, int out_size, void* d_ws, size_t ws_size,
                              hipStream_t stream) {
    const float* X        = (const float*)d_in[0];
    const float* w_reduce = (const float*)d_in[1];
    const float* b_reduce = (const float*)d_in[2];
    const float* gamma    = (const float*)d_in[3];
    const float* beta     = (const float*)d_in[4];
    const float* w_span   = (const float*)d_in[5];
    const float* b_span   = (const float*)d_in[6];
    float* out = (float*)d_out;
    float* ws  = (float*)d_ws;

    if (ws_size >= WS_NEED) {
        float* r_ws    = ws;
        float* partial = ws + R_F;
        float* stats   = ws + R_F + P_F;
        unsigned int* counter = (unsigned int*)(ws + R_F + P_F + 32);

        hipMemsetAsync(counter, 0, sizeof(unsigned int), stream);
        hipFuncSetAttribute((const void*)k_inv2,
                            hipFuncAttributeMaxDynamicSharedMemorySize, SMEM2_BYTES);

        k_reduce_r2<<<512, 256, 0, stream>>>(X, w_reduce, b_reduce, gamma, beta,
                                             r_ws, partial, stats, counter);
        k_inv2<<<512, 256, SMEM2_BYTES, stream>>>(X, r_ws, stats, w_span, b_span, out);
    } else {
        float* partial = ws;
        float* stats   = ws + 8192;
        hipFuncSetAttribute((const void*)k_involution,
                            hipFuncAttributeMaxDynamicSharedMemorySize, SMEM_BYTES);
        k_reduce_stats<<<256, 128, 0, stream>>>(X, w_reduce, b_reduce, partial);
        k_stats_final<<<1, 256, 0, stream>>>(partial, stats);
        k_involution<<<512, 256, SMEM_BYTES, stream>>>(
            X, w_reduce, b_reduce, gamma, beta, w_span, b_span, stats, out);
    }
}

// Round 4
// 35.027 us; speedup vs baseline: 2.8553x; 2.8553x over previous
//
#include <hip/hip_runtime.h>
#include <math.h>

// ---------------- problem constants ----------------
constexpr int B  = 2, C = 64, H = 128, W = 128;
constexpr int Cr = 16;
constexpr int K  = 7, KK = 49;
constexpr int HW  = H * W;
constexpr int CHW = C * HW;
constexpr int NPIX = B * HW;       // 32768
constexpr float EPS = 1e-5f;

// ---- fast-path ws layout (floats): r[NPIX][16] | partial[512*32]
constexpr int R_F = NPIX * Cr;     // 524288
constexpr int P_F = 512 * 32;      // 16384
constexpr size_t WS_NEED = (size_t)(R_F + P_F + 64) * 4;

// ==================== FAST PATH ====================

// A: r = X . w_reduce + b_reduce (+ per-block stats partials). NO fences/atomics.
// grid 512 x 256: block = 64 pixels x 4 channel-groups(16ch).
__global__ __launch_bounds__(256) void k_reduce_r(
    const float* __restrict__ X, const float* __restrict__ w_reduce,
    const float* __restrict__ b_reduce, float* __restrict__ r_ws,
    float* __restrict__ partial)
{
    __shared__ float wrS[Cr * C];
    __shared__ float tmpA[4][Cr][64];
    const int t = threadIdx.x;
    for (int i = t; i < Cr * C; i += 256) wrS[i] = w_reduce[i];
    __syncthreads();

    const int pixl = t & 63, cg = t >> 6;
    const int p = blockIdx.x * 64 + pixl;
    const int b = p >> 14, hw = p & (HW - 1);
    const float* xb = X + (size_t)b * CHW + hw;

    float x[16];
    #pragma unroll
    for (int i = 0; i < 16; ++i) x[i] = xb[(cg * 16 + i) * HW];

    float rp[16];
    #pragma unroll
    for (int o = 0; o < 16; ++o) rp[o] = (cg == 0) ? b_reduce[o] : 0.f;
    #pragma unroll
    for (int i = 0; i < 16; ++i) {
        const float xv = x[i];
        #pragma unroll
        for (int o = 0; o < 16; ++o)
            rp[o] = fmaf(xv, wrS[o * 64 + cg * 16 + i], rp[o]);
    }
    #pragma unroll
    for (int o = 0; o < 16; ++o) tmpA[cg][o][pixl] = rp[o];
    __syncthreads();

    float rr[4];
    #pragma unroll
    for (int j = 0; j < 4; ++j) {
        const int o = cg * 4 + j;
        rr[j] = tmpA[0][o][pixl] + tmpA[1][o][pixl] + tmpA[2][o][pixl] + tmpA[3][o][pixl];
    }
    *(float4*)&r_ws[(size_t)p * 16 + cg * 4] = make_float4(rr[0], rr[1], rr[2], rr[3]);

    float s[4], q[4];
    #pragma unroll
    for (int j = 0; j < 4; ++j) { s[j] = rr[j]; q[j] = rr[j] * rr[j]; }
    #pragma unroll
    for (int off = 32; off > 0; off >>= 1) {
        #pragma unroll
        for (int j = 0; j < 4; ++j) {
            s[j] += __shfl_down(s[j], off);
            q[j] += __shfl_down(q[j], off);
        }
    }
    if ((t & 63) == 0) {
        #pragma unroll
        for (int j = 0; j < 4; ++j) {
            partial[blockIdx.x * 32 + cg * 4 + j]      = s[j];
            partial[blockIdx.x * 32 + 16 + cg * 4 + j] = q[j];
        }
    }
}

// C: per-block redundant stats + fused act/kc(in-reg) + involution.
// block = (b, half(32ch), 16w x 8h tile), 256 thr, grid 512, XCD-swizzled.
constexpr int TLH = 8, TLW = 16;
constexpr int HR = TLH + 6, HC = TLW + 6;    // 14 x 22 halo
constexpr int RPT = 24;
constexpr int CSP = HR * RPT + 4;            // 340
constexpr int XS3_F = 32 * CSP;              // 10880
constexpr int KC3_F = KK * 128;              // 6272
constexpr int SMEM3_F = XS3_F + KC3_F + 256 + 32;   // 17440
constexpr int SMEM3_BYTES = SMEM3_F * 4;            // 69760 -> 2 blocks/CU

__global__ __launch_bounds__(256) void k_inv3(
    const float* __restrict__ X, const float* __restrict__ r_ws,
    const float* __restrict__ partial, const float* __restrict__ gamma,
    const float* __restrict__ beta, const float* __restrict__ w_span,
    const float* __restrict__ b_span, float* __restrict__ out)
{
    extern __shared__ float smem[];
    float* Xs  = smem;               // [c][r*24+col] (+4 pad/ch)
    float* kcS = Xs + XS3_F;         // [k][128 px]
    float* red = kcS + KC3_F;        // [8][32]
    float* scS = red + 256;          // [16]
    float* ofS = scS + 16;           // [16]

    const int t   = threadIdx.x;
    const int raw = blockIdx.x;
    const int wg  = (raw & 7) * 64 + (raw >> 3);   // bijective XCD swizzle (512%8==0)
    const int tile = wg & 127;
    const int half = (wg >> 7) & 1;
    const int b    = wg >> 8;
    const int th0 = (tile >> 3) * TLH;
    const int tw0 = (tile & 7) * TLW;

    // ---- issue r_ws loads for this thread's pixel early ----
    const int px = t & 127;                 // tile pixel (8 rows x 16 cols)
    const int h  = t >> 7;                  // k-range half (uniform per wave)
    const int p1r = px >> 4, p1c = px & 15;
    const size_t gp = (size_t)b * HW + (size_t)(th0 + p1r) * W + (tw0 + p1c);
    const float4 r0 = *(const float4*)&r_ws[gp * 16 + 0];
    const float4 r1 = *(const float4*)&r_ws[gp * 16 + 4];
    const float4 r2 = *(const float4*)&r_ws[gp * 16 + 8];
    const float4 r3 = *(const float4*)&r_ws[gp * 16 + 12];

    // ---- stage X halo (32 ch), async wrt stats below ----
    {
        const int scol = t & 31;
        const int sch  = t >> 5;
        const int gw   = tw0 + scol - 3;
        const bool wok = (unsigned)gw < (unsigned)W;
        const float* xg = X + (size_t)b * CHW + (size_t)(half * 32) * HW;
        #pragma unroll
        for (int cb = 0; cb < 4; ++cb) {
            const int c = cb * 8 + sch;
            const float* xc = xg + (size_t)c * HW;
            float* xs = Xs + c * CSP + scol;
            #pragma unroll
            for (int r = 0; r < HR; ++r) {
                const int gh = th0 + r - 3;
                float v = 0.f;
                if (wok && (unsigned)gh < (unsigned)H) v = xc[gh * W + gw];
                if (scol < HC) xs[r * RPT] = v;
            }
        }
    }

    // ---- redundant per-block stats reduce (fixed order -> deterministic) ----
    {
        const int o = t & 31, seg = t >> 5;
        float acc = 0.f;
        #pragma unroll 16
        for (int j = 0; j < 64; ++j) acc += partial[(size_t)(seg * 64 + j) * 32 + o];
        red[seg * 32 + o] = acc;
    }
    __syncthreads();                         // sync1: red ready (Xs writes still fine)
    if (t < 64) {                            // wave 0 finalizes
        const int o2 = t & 31;
        float tot = 0.f;
        #pragma unroll
        for (int g = 0; g < 8; ++g) tot += red[g * 32 + o2];
        const float sq = __shfl(tot, (t & 31) + 16);   // lane o<16 gets sumsq[o]
        if (t < 16) {
            const float mean = tot / (float)NPIX;
            const float var  = sq / (float)NPIX - mean * mean;
            const float sc   = gamma[t] * rsqrtf(var + EPS);
            scS[t] = sc;
            ofS[t] = beta[t] - mean * sc;
        }
    }
    __syncthreads();                         // sync2: sc/of ready

    // ---- act (regs) + kc (this thread's k-range) ----
    {
        float act[16];
        const float rv[16] = {r0.x, r0.y, r0.z, r0.w, r1.x, r1.y, r1.z, r1.w,
                              r2.x, r2.y, r2.z, r2.w, r3.x, r3.y, r3.z, r3.w};
        #pragma unroll
        for (int o = 0; o < 16; ++o)
            act[o] = fmaxf(fmaf(scS[o], rv[o], ofS[o]), 0.f);
        #pragma unroll
        for (int j = 0; j < 25; ++j) {
            const int k = h * 25 + j;        // uniform per wave
            if (k < KK) {
                float v = b_span[k];         // scalar load
                #pragma unroll
                for (int o = 0; o < 16; ++o)
                    v = fmaf(act[o], w_span[k * 16 + o], v);   // scalar loads
                kcS[k * 128 + px] = v;
            }
        }
    }
    __syncthreads();                         // sync3: kcS + Xs ready

    // ---- involution: thread = 4px x 4ch ----
    const int strip = t & 31;
    const int chg   = t >> 5;
    const int pr3 = strip >> 2, pc = (strip & 3) * 4;
    const int c0  = chg * 4;

    float acc[4][4];
    #pragma unroll
    for (int i = 0; i < 4; ++i)
        #pragma unroll
        for (int j = 0; j < 4; ++j) acc[i][j] = 0.f;

    #pragma unroll
    for (int kh = 0; kh < 7; ++kh) {
        float4 kcr[7];
        #pragma unroll
        for (int kw = 0; kw < 7; ++kw)
            kcr[kw] = *(const float4*)&kcS[(kh * 7 + kw) * 128 + pr3 * 16 + pc];
        const float* kf = (const float*)kcr;
        #pragma unroll
        for (int i = 0; i < 4; ++i) {
            const float* xr = &Xs[(c0 + i) * CSP + (pr3 + kh) * RPT + pc];
            const float4 xa = *(const float4*)&xr[0];
            const float4 xb = *(const float4*)&xr[4];
            const float4 xc = *(const float4*)&xr[8];
            const float xw[12] = {xa.x, xa.y, xa.z, xa.w,
                                  xb.x, xb.y, xb.z, xb.w,
                                  xc.x, xc.y, xc.z, xc.w};
            #pragma unroll
            for (int kw = 0; kw < 7; ++kw)
                #pragma unroll
                for (int j = 0; j < 4; ++j)
                    acc[i][j] = fmaf(kf[kw * 4 + j], xw[kw + j], acc[i][j]);
        }
    }

    float* ob = out + (size_t)b * CHW + (size_t)(half * 32 + c0) * HW
                    + (size_t)(th0 + pr3) * W + (tw0 + pc);
    #pragma unroll
    for (int i = 0; i < 4; ++i)
        *(float4*)&ob[(size_t)i * HW] = make_float4(acc[i][0], acc[i][1], acc[i][2], acc[i][3]);
}

// ==================== FALLBACK PATH (round-1, passing) ====================

constexpr int XS_F  = C * 196;
constexpr int KC_F  = KK * 64;
constexpr int ACT_F = Cr * 64;
constexpr int WR_F  = Cr * C;
constexpr int WSP_F = KK * Cr;
constexpr int SMEM_F = XS_F + KC_F + ACT_F + WR_F + WSP_F + KK + Cr + Cr;
constexpr int SMEM_BYTES = SMEM_F * 4;

__global__ __launch_bounds__(128) void k_reduce_stats(
    const float* __restrict__ X, const float* __restrict__ w_reduce,
    const float* __restrict__ b_reduce, float* __restrict__ partial)
{
    __shared__ float wr[WR_F];
    __shared__ float brd[Cr];
    __shared__ float tmp[2][32];
    const int t = threadIdx.x;
    for (int i = t; i < WR_F; i += 128) wr[i] = w_reduce[i];
    if (t < Cr) brd[t] = b_reduce[t];
    __syncthreads();
    const int p  = blockIdx.x * 128 + t;
    const int b  = p >> 14;
    const int hw = p & (HW - 1);
    const float* xb = X + b * CHW + hw;
    float r[Cr];
    #pragma unroll
    for (int o = 0; o < Cr; ++o) r[o] = brd[o];
    #pragma unroll 4
    for (int c = 0; c < C; ++c) {
        const float x = xb[c * HW];
        #pragma unroll
        for (int o = 0; o < Cr; ++o) r[o] = fmaf(x, wr[o * C + c], r[o]);
    }
    const int lane = t & 63, wv = t >> 6;
    #pragma unroll
    for (int o = 0; o < Cr; ++o) {
        float s = r[o], q = r[o] * r[o];
        #pragma unroll
        for (int off = 32; off > 0; off >>= 1) {
            s += __shfl_down(s, off);
            q += __shfl_down(q, off);
        }
        if (lane == 0) { tmp[wv][o] = s; tmp[wv][Cr + o] = q; }
    }
    __syncthreads();
    if (t < 32) partial[blockIdx.x * 32 + t] = tmp[0][t] + tmp[1][t];
}

__global__ __launch_bounds__(256) void k_stats_final(
    const float* __restrict__ partial, float* __restrict__ stats)
{
    __shared__ float red[256];
    __shared__ float fin[32];
    const int t = threadIdx.x;
    const int o = t & 31, g = t >> 5;
    float acc = 0.f;
    #pragma unroll 8
    for (int j = 0; j < 32; ++j) acc += partial[(g * 32 + j) * 32 + o];
    red[t] = acc;
    __syncthreads();
    if (t < 32) {
        float v = 0.f;
        #pragma unroll
        for (int g2 = 0; g2 < 8; ++g2) v += red[g2 * 32 + t];
        fin[t] = v;
    }
    __syncthreads();
    if (t < Cr) {
        const float mean = fin[t] / (float)NPIX;
        const float var  = fin[Cr + t] / (float)NPIX - mean * mean;
        stats[t]      = mean;
        stats[Cr + t] = rsqrtf(var + EPS);
    }
}

__global__ __launch_bounds__(256) void k_involution(
    const float* __restrict__ X, const float* __restrict__ w_reduce,
    const float* __restrict__ b_reduce, const float* __restrict__ gamma,
    const float* __restrict__ beta, const float* __restrict__ w_span,
    const float* __restrict__ b_span, const float* __restrict__ stats,
    float* __restrict__ out)
{
    extern __shared__ float smem[];
    float* Xs   = smem;
    float* kcS  = Xs  + XS_F;
    float* actS = kcS + KC_F;
    float* wrS  = actS + ACT_F;
    float* wspS = wrS + WR_F;
    float* bspS = wspS + WSP_F;
    float* scS  = bspS + KK;
    float* ofS  = scS + Cr;
    const int t    = threadIdx.x;
    const int bx   = blockIdx.x;
    const int b    = bx >> 8;
    const int tile = bx & 255;
    const int h0   = (tile >> 4) << 3;
    const int w0   = (tile & 15) << 3;
    const float* xbg = X + b * CHW;
    for (int idx = t; idx < XS_F; idx += 256) {
        const int c   = idx / 196;
        const int rem = idx - c * 196;
        const int r   = rem / 14;
        const int col = rem - r * 14;
        const int gh  = h0 + r - 3, gw = w0 + col - 3;
        float v = 0.f;
        if ((unsigned)gh < (unsigned)H && (unsigned)gw < (unsigned)W)
            v = xbg[c * HW + gh * W + gw];
        Xs[idx] = v;
    }
    for (int i = t; i < WR_F;  i += 256) wrS[i]  = w_reduce[i];
    for (int i = t; i < WSP_F; i += 256) wspS[i] = w_span[i];
    if (t < KK) bspS[t] = b_span[t];
    if (t < Cr) {
        const float m  = stats[t];
        const float rs = stats[Cr + t];
        const float gm = gamma[t];
        scS[t] = gm * rs;
        ofS[t] = (b_reduce[t] - m) * gm * rs + beta[t];
    }
    __syncthreads();
    const int pix = t & 63;
    const int grp = t >> 6;
    const int ph  = pix >> 3, pw = pix & 7;
    {
        const int base = (ph + 3) * 14 + (pw + 3);
        float d0 = 0.f, d1 = 0.f, d2 = 0.f, d3 = 0.f;
        #pragma unroll 8
        for (int c = 0; c < C; ++c) {
            const float x = Xs[c * 196 + base];
            d0 = fmaf(x, wrS[(grp * 4 + 0) * C + c], d0);
            d1 = fmaf(x, wrS[(grp * 4 + 1) * C + c], d1);
            d2 = fmaf(x, wrS[(grp * 4 + 2) * C + c], d2);
            d3 = fmaf(x, wrS[(grp * 4 + 3) * C + c], d3);
        }
        const float d[4] = {d0, d1, d2, d3};
        #pragma unroll
        for (int j = 0; j < 4; ++j) {
            const int o = grp * 4 + j;
            actS[o * 64 + pix] = fmaxf(fmaf(scS[o], d[j], ofS[o]), 0.f);
        }
    }
    __syncthreads();
    for (int k = grp; k < KK; k += 4) {
        float v = bspS[k];
        #pragma unroll
        for (int o = 0; o < Cr; ++o)
            v = fmaf(actS[o * 64 + pix], wspS[k * Cr + o], v);
        kcS[k * 64 + pix] = v;
    }
    __syncthreads();
    float acc[16];
    #pragma unroll
    for (int i = 0; i < 16; ++i) acc[i] = 0.f;
    const float* xsc = Xs + grp * 16 * 196;
    #pragma unroll
    for (int k = 0; k < KK; ++k) {
        const int kh = k / 7, kw = k - (k / 7) * 7;
        const float kcv = kcS[k * 64 + pix];
        const int xoff = (ph + kh) * 14 + (pw + kw);
        #pragma unroll
        for (int i = 0; i < 16; ++i)
            acc[i] = fmaf(kcv, xsc[i * 196 + xoff], acc[i]);
    }
    float* ob = out + b * CHW + (grp * 16) * HW + (h0 + ph) * W + (w0 + pw);
    #pragma unroll
    for (int i = 0; i < 16; ++i) ob[i * HW] = acc[i];
}

// ==================== launch ====================

extern "C" void kernel_launch(void* const* d_in, const int* in_sizes, int n_in,
                              void* d_out, int out_size, void* d_ws, size_t ws_size,
                              hipStream_t stream) {
    const float* X        = (const float*)d_in[0];
    const float* w_reduce = (const float*)d_in[1];
    const float* b_reduce = (const float*)d_in[2];
    const float* gamma    = (const float*)d_in[3];
    const float* beta     = (const float*)d_in[4];
    const float* w_span   = (const float*)d_in[5];
    const float* b_span   = (const float*)d_in[6];
    float* out = (float*)d_out;
    float* ws  = (float*)d_ws;

    if (ws_size >= WS_NEED) {
        float* r_ws    = ws;
        float* partial = ws + R_F;
        hipFuncSetAttribute((const void*)k_inv3,
                            hipFuncAttributeMaxDynamicSharedMemorySize, SMEM3_BYTES);
        k_reduce_r<<<512, 256, 0, stream>>>(X, w_reduce, b_reduce, r_ws, partial);
        k_inv3<<<512, 256, SMEM3_BYTES, stream>>>(X, r_ws, partial, gamma, beta,
                                                  w_span, b_span, out);
    } else {
        float* partial = ws;
        float* stats   = ws + 8192;
        hipFuncSetAttribute((const void*)k_involution,
                            hipFuncAttributeMaxDynamicSharedMemorySize, SMEM_BYTES);
        k_reduce_stats<<<256, 128, 0, stream>>>(X, w_reduce, b_reduce, partial);
        k_stats_final<<<1, 256, 0, stream>>>(partial, stats);
        k_involution<<<512, 256, SMEM_BYTES, stream>>>(
            X, w_reduce, b_reduce, gamma, beta, w_span, b_span, stats, out);
    }
}